// Round 1
// 11343.336 us; speedup vs baseline: 1.2255x; 1.2255x over previous
//
#include <hip/hip_runtime.h>

typedef unsigned short u16;
typedef unsigned long long u64;
typedef __bf16 bf16x8 __attribute__((ext_vector_type(8)));
typedef float f32x4 __attribute__((ext_vector_type(4)));

constexpr int kB = 64;       // batch
constexpr int kT = 1024;     // timesteps
constexpr int kD = 512;      // input dim
constexpr int kU = 1024;     // hidden units
constexpr int kK = kD + kU;  // 1536 total contraction
constexpr int kNG = 256;     // workgroups == column groups (4 u each)
constexpr int kNC = 16;      // gate columns per WG (4 u * 4 gates)

// ---- workspace layout (bytes) ----
// barrier region: 16 leaf counters at i*128B, root @2048, flag @2176
constexpr size_t OFF_BAR = 0;
constexpr size_t OFF_H   = 4096;                               // double-buffered h, bf16 [2][B][U]
constexpr size_t OFF_W   = OFF_H + 2ull * kB * kU * 2;         // permuted W bf16 [NG][K][NC]
constexpr size_t OFF_X   = OFF_W + (size_t)kNG * kK * kNC * 2; // x bf16 [T][B][D]

// ---------- prologue: permute + bf16-convert weights ----------
// Wperm[g][k][c] = kernel[k][ (c>>2)*U + g*4 + (c&3) ]
__global__ void prep_w(const float* __restrict__ kern, u16* __restrict__ wperm) {
    const int g = blockIdx.x;
    const int c = threadIdx.x & 15;
    const int k = blockIdx.y * 16 + (threadIdx.x >> 4);
    const int gate = c >> 2, uu = c & 3;
    float v = kern[(size_t)k * (4 * kU) + gate * kU + g * 4 + uu];
    __bf16 b = (__bf16)v;
    wperm[((size_t)g * kK + k) * kNC + c] = *(u16*)&b;
}

// ---------- prologue: transpose + bf16-convert inputs ----------
// xbf[t][b][d] = bf16(inputs[b][t][d])
__global__ void prep_x(const float* __restrict__ inp, u16* __restrict__ xbf) {
    const int idx = blockIdx.x * 256 + threadIdx.x;   // < T*B*D = 33554432
    const int d = idx & (kD - 1);
    const int r = idx >> 9;
    const int b = r & (kB - 1);
    const int t = r >> 6;
    float v = inp[((size_t)b * kT + t) * kD + d];
    __bf16 bb = (__bf16)v;
    xbf[idx] = *(u16*)&bb;
}

// ---------- persistent LSTM kernel ----------
// grid = 256 WGs (one per CU), block = 1024 threads (16 waves).
// wave wid: mt = wid&3 (16-row batch tile), kg = wid>>2 (384-wide K slice).
// h producers store via sc1 (straight to L3, never dirty in any L2).
// h consumers use NORMAL cached loads; a per-step agent-acquire fence
// (buffer_inv) drops the previous step's stale clean lines, so the 32 WGs
// per XCD share one L3 fetch of h through their common L2 (32x traffic cut
// vs the old sc1 load path).
__global__ __launch_bounds__(1024) void lstm_persist(
        const u16* __restrict__ wperm,
        const u16* __restrict__ xbf,
        u16* __restrict__ hbuf,
        const float* __restrict__ bias,
        float* __restrict__ out,
        unsigned* __restrict__ barv)   // leaf[i] @ i*32 (u32 idx), root @512, flag @544
{
    __shared__ float part[4][64][17];  // [kg][m][c], +1 pad vs bank conflicts
    __shared__ float cst[64][4];       // cell state c[m][uu], persistent in LDS
    __shared__ float biasv[16];

    const int g    = blockIdx.x;
    const int tid  = threadIdx.x;
    const int lane = tid & 63;
    const int wid  = tid >> 6;
    const int mt   = wid & 3;
    const int kg   = wid >> 2;

    const int n    = lane & 15;
    const int kq   = (lane >> 4) * 8;
    const int mrow = mt * 16 + (lane & 15);

    unsigned* leaf = barv + (size_t)(g >> 4) * 32;  // 16 WGs per leaf line
    unsigned* root = barv + 512;
    unsigned* flag = barv + 544;

    // --- load this wave's 12 W B-fragments once (gather from permuted W) ---
    bf16x8 wf[12];
    {
        const u16* Wg = wperm + (size_t)g * (kK * kNC);
        #pragma unroll
        for (int ks = 0; ks < 12; ++ks) {
            const int kb = kg * 384 + ks * 32 + kq;
            union { u16 u[8]; bf16x8 v; } tmp;
            #pragma unroll
            for (int j = 0; j < 8; ++j) tmp.u[j] = Wg[(size_t)(kb + j) * kNC + n];
            wf[ks] = tmp.v;
        }
    }

    if (tid < 256) cst[tid >> 2][tid & 3] = 0.f;
    if (tid < 16) {
        const int gate = tid >> 2, uu = tid & 3;
        biasv[tid] = bias[gate * kU + g * 4 + uu];
    }
    __syncthreads();

    for (int t = 0; t < kT; ++t) {
        const u16* hcur = hbuf + (size_t)(t & 1) * (kB * kU);
        const u16* xrow = xbf + ((size_t)t * kB + mrow) * kD;
        const u16* hrow = hcur + (size_t)mrow * kU;

        // --- phase 1: gather all 12 A-fragments ---
        // x: normal cached loads (L3-resident, L2-amplified).
        // h: normal cached loads; freshness guaranteed by the per-step
        //    acquire fence below. t==0: h is all-zero -> skip (also removes
        //    any dependence on h0 initialization visibility).
        bf16x8 af[12];
        #pragma unroll
        for (int ks = 0; ks < 12; ++ks) {
            const int kb = kg * 384 + ks * 32;   // 32-chunk never straddles x/h split
            if (kb < kD) {
                af[ks] = *(const bf16x8*)(xrow + kb + kq);
            } else if (t == 0) {
                union { u64 q[2]; bf16x8 v; } z;
                z.q[0] = 0; z.q[1] = 0;
                af[ks] = z.v;
            } else {
                af[ks] = *(const bf16x8*)(hrow + (kb - kD) + kq);
            }
        }

        // --- phase 2: MFMA chain over this wave's K slice ---
        f32x4 acc = {0.f, 0.f, 0.f, 0.f};
        #pragma unroll
        for (int ks = 0; ks < 12; ++ks)
            acc = __builtin_amdgcn_mfma_f32_16x16x32_bf16(af[ks], wf[ks], acc, 0, 0, 0);

        // --- spill partials to LDS ---
        {
            const int col   = lane & 15;
            const int rbase = mt * 16 + (lane >> 4) * 4;
            #pragma unroll
            for (int r = 0; r < 4; ++r) part[kg][rbase + r][col] = acc[r];
        }
        __syncthreads();

        // --- reduce 4 K-partials + elementwise LSTM cell (threads 0..255) ---
        if (tid < 256) {
            const int m = tid >> 2, uu = tid & 3;
            float gv[4];
            #pragma unroll
            for (int gate = 0; gate < 4; ++gate) {
                const int c = gate * 4 + uu;
                gv[gate] = part[0][m][c] + part[1][m][c] +
                           part[2][m][c] + part[3][m][c] + biasv[c];
            }
            const float cold = cst[m][uu];
            const float si = 1.f / (1.f + __expf(-gv[0]));
            const float tj = tanhf(gv[1]);
            const float sf = 1.f / (1.f + __expf(-(gv[2] + 1.f)));  // forget_bias=1
            const float so = 1.f / (1.f + __expf(-gv[3]));
            const float cnew = cold * sf + si * tj;
            const float hnew = tanhf(cnew) * so;
            cst[m][uu] = cnew;

            const int u = g * 4 + uu;
            out[((size_t)m * kT + t) * kU + u] = hnew;

            // pack 2 adjacent bf16 h-values, even threads store u32 via sc1 atomic
            // (bypasses producer L2 -> h lands at L3, never dirty in any L2)
            __bf16 hb = (__bf16)hnew;
            unsigned hbits = (unsigned)*(u16*)&hb;
            unsigned nbits = __shfl_down(hbits, 1);
            if ((tid & 1) == 0) {
                unsigned packed = hbits | (nbits << 16);
                u16* hnx = hbuf + (size_t)((t + 1) & 1) * (kB * kU);
                unsigned* dst = (unsigned*)hnx + ((size_t)m * kU + u) / 2;
                __hip_atomic_store(dst, packed, __ATOMIC_RELAXED, __HIP_MEMORY_SCOPE_AGENT);
            }
        }
        // drains vmcnt for every wave => all h stores visible at L3 before arrival
        __syncthreads();

        // --- grid barrier: 2-level arrival (16 leaf lines -> root -> flag) ---
        if (t + 1 < kT) {
            if (tid == 0) {
                unsigned oldl = __hip_atomic_fetch_add(leaf, 1u,
                                    __ATOMIC_RELAXED, __HIP_MEMORY_SCOPE_AGENT);
                if (oldl == (unsigned)(16 * (t + 1) - 1)) {
                    unsigned oldr = __hip_atomic_fetch_add(root, 1u,
                                        __ATOMIC_RELAXED, __HIP_MEMORY_SCOPE_AGENT);
                    if (oldr == (unsigned)(16 * (t + 1) - 1)) {
                        __hip_atomic_store(flag, (unsigned)(t + 1),
                                           __ATOMIC_RELAXED, __HIP_MEMORY_SCOPE_AGENT);
                    }
                }
                while (__hip_atomic_load(flag, __ATOMIC_RELAXED,
                                         __HIP_MEMORY_SCOPE_AGENT) < (unsigned)(t + 1)) {
                    __builtin_amdgcn_s_sleep(2);
                }
                // agent acquire: buffer_inv drops stale clean h/x lines from
                // this XCD's L2 before anyone here reads h(t+1). Dirty lines
                // (out writes) are not discarded by inv.
                __builtin_amdgcn_fence(__ATOMIC_ACQUIRE, "agent");
            }
            __syncthreads();
        }
    }
}

extern "C" void kernel_launch(void* const* d_in, const int* in_sizes, int n_in,
                              void* d_out, int out_size, void* d_ws, size_t ws_size,
                              hipStream_t stream) {
    const float* inputs = (const float*)d_in[0];
    const float* kern   = (const float*)d_in[1];
    const float* bias   = (const float*)d_in[2];
    float* out = (float*)d_out;

    char* ws = (char*)d_ws;
    unsigned* barv = (unsigned*)(ws + OFF_BAR);
    u16* hbuf  = (u16*)(ws + OFF_H);
    u16* wperm = (u16*)(ws + OFF_W);
    u16* xbf   = (u16*)(ws + OFF_X);

    // zero barrier state (h0 never read: t==0 skips h fragments)
    hipMemsetAsync(ws, 0, OFF_H, stream);

    prep_w<<<dim3(kNG, kK / 16), 256, 0, stream>>>(kern, wperm);
    prep_x<<<(kT * kB * kD) / 256, 256, 0, stream>>>(inputs, xbf);

    const u16* wperm_c = wperm;
    const u16* xbf_c   = xbf;
    void* args[] = { (void*)&wperm_c, (void*)&xbf_c, (void*)&hbuf,
                     (void*)&bias, (void*)&out, (void*)&barv };
    hipLaunchCooperativeKernel((void*)lstm_persist, dim3(kNG), dim3(1024),
                               args, 0, stream);
}

// Round 2
// 7805.098 us; speedup vs baseline: 1.7810x; 1.4533x over previous
//
#include <hip/hip_runtime.h>

typedef unsigned short u16;
typedef unsigned long long u64;
typedef __bf16 bf16x8 __attribute__((ext_vector_type(8)));
typedef float f32x4 __attribute__((ext_vector_type(4)));

constexpr int kB = 64;       // batch
constexpr int kT = 1024;     // timesteps
constexpr int kD = 512;      // input dim
constexpr int kU = 1024;     // hidden units
constexpr int kK = kD + kU;  // 1536 total contraction
constexpr int kNG = 256;     // Wperm column groups (4 u each)
constexpr int kNC = 16;      // gate columns per group (4 u * 4 gates)

// 4 independent batch groups (16 rows each) x 64 WGs (64 gate-cols each)
constexpr int kGroups = 4;
constexpr int kWGperG = 64;

// ---- workspace layout (bytes) ----
// barrier region: per group g (1KB apart): leaf[l] @ g*1024 + l*128 (l=0..3),
// root @ g*1024+512, flag @ g*1024+640
constexpr size_t OFF_BAR = 0;
constexpr size_t OFF_H   = 8192;                               // double-buffered h, bf16 [2][B][U]
constexpr size_t OFF_W   = OFF_H + 2ull * kB * kU * 2;         // permuted W bf16 [NG][K][NC]
constexpr size_t OFF_X   = OFF_W + (size_t)kNG * kK * kNC * 2; // x bf16 [T][B][D]

// ---------- prologue: permute + bf16-convert weights ----------
// Wperm[g][k][c] = kernel[k][ (c>>2)*U + g*4 + (c&3) ]
__global__ void prep_w(const float* __restrict__ kern, u16* __restrict__ wperm) {
    const int g = blockIdx.x;
    const int c = threadIdx.x & 15;
    const int k = blockIdx.y * 16 + (threadIdx.x >> 4);
    const int gate = c >> 2, uu = c & 3;
    float v = kern[(size_t)k * (4 * kU) + gate * kU + g * 4 + uu];
    __bf16 b = (__bf16)v;
    wperm[((size_t)g * kK + k) * kNC + c] = *(u16*)&b;
}

// ---------- prologue: transpose + bf16-convert inputs ----------
// xbf[t][b][d] = bf16(inputs[b][t][d])
__global__ void prep_x(const float* __restrict__ inp, u16* __restrict__ xbf) {
    const int idx = blockIdx.x * 256 + threadIdx.x;   // < T*B*D = 33554432
    const int d = idx & (kD - 1);
    const int r = idx >> 9;
    const int b = r & (kB - 1);
    const int t = r >> 6;
    float v = inp[((size_t)b * kT + t) * kD + d];
    __bf16 bb = (__bf16)v;
    xbf[idx] = *(u16*)&bb;
}

// ---------- persistent LSTM kernel ----------
// grid = 256 WGs, block = 1024 threads (16 waves).
// Batch group grp = bid>>6 owns rows [grp*16, grp*16+16); column group
// wgc = bid&63 owns gate-cols [wgc*16*4 span] = u in [wgc*16, wgc*16+16).
// Waves: kg = wid&3 (K slice: x 128 + h 256), ntile = wid>>2 (16-col tile).
// Groups synchronize INDEPENDENTLY (64-WG barriers) since the recurrence is
// batch-row-local. x-part MFMAs for t+1 run under the barrier wait.
__global__ __launch_bounds__(1024) void lstm_persist(
        const u16* __restrict__ wperm,
        const u16* __restrict__ xbf,
        u16* __restrict__ hbuf,
        const float* __restrict__ bias,
        float* __restrict__ out,
        unsigned* __restrict__ barv)
{
    __shared__ float part[4][4][16][17];  // [kg][ntile][m][c], +1 pad
    __shared__ float cst[16][16];         // cell state [m][u_local]
    __shared__ float biasv[64];           // [ntile*16 + c]

    const int bid  = blockIdx.x;
    const int grp  = bid >> 6;            // batch group 0..3
    const int wgc  = bid & 63;            // column group 0..63
    const int tid  = threadIdx.x;
    const int lane = tid & 63;
    const int wid  = tid >> 6;
    const int kg   = wid & 3;
    const int ntile= wid >> 2;
    const int gcol = wgc * 4 + ntile;     // Wperm g index

    const int n    = lane & 15;
    const int kq   = (lane >> 4) * 8;
    const int mrow = grp * 16 + (lane & 15);

    unsigned* leaf = barv + (size_t)grp * 256 + (size_t)(wgc >> 4) * 32;
    unsigned* root = barv + (size_t)grp * 256 + 128;
    unsigned* flag = barv + (size_t)grp * 256 + 160;

    // --- load this wave's W B-fragments once: x-part 4, h-part 8 ---
    bf16x8 wfx[4], wfh[8];
    {
        const u16* Wg = wperm + (size_t)gcol * (kK * kNC);
        #pragma unroll
        for (int ks = 0; ks < 4; ++ks) {
            const int kb = kg * 128 + ks * 32 + kq;
            union { u16 u[8]; bf16x8 v; } tmp;
            #pragma unroll
            for (int j = 0; j < 8; ++j) tmp.u[j] = Wg[(size_t)(kb + j) * kNC + n];
            wfx[ks] = tmp.v;
        }
        #pragma unroll
        for (int ks = 0; ks < 8; ++ks) {
            const int kb = kD + kg * 256 + ks * 32 + kq;
            union { u16 u[8]; bf16x8 v; } tmp;
            #pragma unroll
            for (int j = 0; j < 8; ++j) tmp.u[j] = Wg[(size_t)(kb + j) * kNC + n];
            wfh[ks] = tmp.v;
        }
    }

    if (tid < 256) cst[tid >> 4][tid & 15] = 0.f;
    if (tid < 64) {
        const int nt2 = tid >> 4, c = tid & 15;
        const int gate = c >> 2, uq = c & 3;
        biasv[tid] = bias[gate * kU + wgc * 16 + nt2 * 4 + uq];
    }
    __syncthreads();

    // --- prologue: x-part partials for t=0 ---
    f32x4 acc = {0.f, 0.f, 0.f, 0.f};
    {
        const u16* xrow = xbf + (size_t)mrow * kD;
        #pragma unroll
        for (int ks = 0; ks < 4; ++ks) {
            bf16x8 a = *(const bf16x8*)(xrow + kg * 128 + ks * 32 + kq);
            acc = __builtin_amdgcn_mfma_f32_16x16x32_bf16(a, wfx[ks], acc, 0, 0, 0);
        }
    }

    for (int t = 0; t < kT; ++t) {
        // --- h-part: 8 cached loads + 8 MFMAs (skip t=0: h=0) ---
        if (t > 0) {
            const u16* hrow = hbuf + (size_t)(t & 1) * (kB * kU) + (size_t)mrow * kU;
            bf16x8 ah[8];
            #pragma unroll
            for (int ks = 0; ks < 8; ++ks)
                ah[ks] = *(const bf16x8*)(hrow + kg * 256 + ks * 32 + kq);
            #pragma unroll
            for (int ks = 0; ks < 8; ++ks)
                acc = __builtin_amdgcn_mfma_f32_16x16x32_bf16(ah[ks], wfh[ks], acc, 0, 0, 0);
        }

        // --- spill partials to LDS ---
        {
            const int col   = lane & 15;
            const int rbase = (lane >> 4) * 4;
            #pragma unroll
            for (int r = 0; r < 4; ++r) part[kg][ntile][rbase + r][col] = acc[r];
        }
        __syncthreads();

        // --- reduce 4 K-partials + elementwise LSTM cell (threads 0..255) ---
        if (tid < 256) {
            const int m = tid >> 4, uu = tid & 15;
            const int nt2 = uu >> 2, uq = uu & 3;
            float gv[4];
            #pragma unroll
            for (int gate = 0; gate < 4; ++gate) {
                const int c = gate * 4 + uq;
                gv[gate] = part[0][nt2][m][c] + part[1][nt2][m][c] +
                           part[2][nt2][m][c] + part[3][nt2][m][c] + biasv[nt2 * 16 + c];
            }
            const float cold = cst[m][uu];
            const float si = 1.f / (1.f + __expf(-gv[0]));
            const float ej = __expf(2.f * gv[1]);
            const float tj = 1.f - 2.f / (ej + 1.f);
            const float sf = 1.f / (1.f + __expf(-(gv[2] + 1.f)));  // forget_bias=1
            const float so = 1.f / (1.f + __expf(-gv[3]));
            const float cnew = cold * sf + si * tj;
            const float ec = __expf(2.f * cnew);
            const float hnew = (1.f - 2.f / (ec + 1.f)) * so;
            cst[m][uu] = cnew;

            const int u    = wgc * 16 + uu;
            const int grow = grp * 16 + m;
            __builtin_nontemporal_store(hnew, &out[((size_t)grow * kT + t) * kU + u]);

            // pack 2 adjacent bf16 h-values, even threads store u32 via sc1 atomic
            // (straight to L3, h is never dirty in any L2)
            __bf16 hb = (__bf16)hnew;
            unsigned hbits = (unsigned)*(u16*)&hb;
            unsigned nbits = __shfl_down(hbits, 1);
            if ((tid & 1) == 0) {
                unsigned packed = hbits | (nbits << 16);
                u16* hnx = hbuf + (size_t)((t + 1) & 1) * (kB * kU);
                unsigned* dst = (unsigned*)hnx + ((size_t)grow * kU + u) / 2;
                __hip_atomic_store(dst, packed, __ATOMIC_RELAXED, __HIP_MEMORY_SCOPE_AGENT);
            }
        }
        // drains vmcnt for every wave => all h stores at L3 before arrival
        __syncthreads();

        // --- per-group barrier + x-part overlap for t+1 ---
        if (t + 1 < kT) {
            if (tid == 0) {
                unsigned oldl = __hip_atomic_fetch_add(leaf, 1u,
                                    __ATOMIC_RELAXED, __HIP_MEMORY_SCOPE_AGENT);
                if (oldl == (unsigned)(16 * (t + 1) - 1)) {
                    unsigned oldr = __hip_atomic_fetch_add(root, 1u,
                                        __ATOMIC_RELAXED, __HIP_MEMORY_SCOPE_AGENT);
                    if (oldr == (unsigned)(4 * (t + 1) - 1)) {
                        __hip_atomic_store(flag, (unsigned)(t + 1),
                                           __ATOMIC_RELAXED, __HIP_MEMORY_SCOPE_AGENT);
                    }
                }
            }

            // overlap under the wait: x-part partials for t+1 (x is constant,
            // so pre-fence loads are safe; results live in registers)
            {
                const u16* xrow = xbf + ((size_t)(t + 1) * kB + mrow) * kD;
                bf16x8 ax[4];
                #pragma unroll
                for (int ks = 0; ks < 4; ++ks)
                    ax[ks] = *(const bf16x8*)(xrow + kg * 128 + ks * 32 + kq);
                acc = (f32x4){0.f, 0.f, 0.f, 0.f};
                #pragma unroll
                for (int ks = 0; ks < 4; ++ks)
                    acc = __builtin_amdgcn_mfma_f32_16x16x32_bf16(ax[ks], wfx[ks], acc, 0, 0, 0);
            }

            if (tid == 0) {
                while (__hip_atomic_load(flag, __ATOMIC_RELAXED,
                                         __HIP_MEMORY_SCOPE_AGENT) < (unsigned)(t + 1)) {
                    __builtin_amdgcn_s_sleep(2);
                }
                // agent acquire: drop stale clean h lines from this XCD's L2
                __builtin_amdgcn_fence(__ATOMIC_ACQUIRE, "agent");
            }
            __syncthreads();
        }
    }
}

extern "C" void kernel_launch(void* const* d_in, const int* in_sizes, int n_in,
                              void* d_out, int out_size, void* d_ws, size_t ws_size,
                              hipStream_t stream) {
    const float* inputs = (const float*)d_in[0];
    const float* kern   = (const float*)d_in[1];
    const float* bias   = (const float*)d_in[2];
    float* out = (float*)d_out;

    char* ws = (char*)d_ws;
    unsigned* barv = (unsigned*)(ws + OFF_BAR);
    u16* hbuf  = (u16*)(ws + OFF_H);
    u16* wperm = (u16*)(ws + OFF_W);
    u16* xbf   = (u16*)(ws + OFF_X);

    // zero barrier state (h0 never read: t==0 skips h fragments)
    hipMemsetAsync(ws, 0, OFF_H, stream);

    prep_w<<<dim3(kNG, kK / 16), 256, 0, stream>>>(kern, wperm);
    prep_x<<<(kT * kB * kD) / 256, 256, 0, stream>>>(inputs, xbf);

    const u16* wperm_c = wperm;
    const u16* xbf_c   = xbf;
    void* args[] = { (void*)&wperm_c, (void*)&xbf_c, (void*)&hbuf,
                     (void*)&bias, (void*)&out, (void*)&barv };
    hipLaunchCooperativeKernel((void*)lstm_persist, dim3(kGroups * kWGperG), dim3(1024),
                               args, 0, stream);
}